// Round 4
// baseline (280.772 us; speedup 1.0000x reference)
//
#include <hip/hip_runtime.h>

#define T 15
#define HIN 256
#define C1N 32
#define C2N 150
#define CHW 256              // conv1 output spatial
#define PP 129               // pooled spatial
#define PADP 131             // padded pooled
#define HO 130               // conv2 output spatial
#define POS2 (HO*HO)         // 16900
#define POS4 (POS2/4)        // 4225
#define NPOT2 (T*C2N*POS2)   // 38,025,000

// ---------------------------------------------------------------- k0: first-spike time per input pixel
__global__ void k_tfirst(const float* __restrict__ in, int* __restrict__ tf) {
  int i = blockIdx.x * 256 + threadIdx.x;
  if (i >= 2 * HIN * HIN) return;
  float s = 0.f;
#pragma unroll
  for (int t = 0; t < T; t++) s += in[t * (2 * HIN * HIN) + i];
  tf[i] = T - (int)(s + 0.5f);   // cumulative binary input: sum = #active steps
}

// ---------------------------------------------------------------- k1: conv1 + fire(10), LDS-staged taps, 4 channels/thread
// block = 256 threads (one row of w), grid = (256 rows, 8 channel-groups)
__global__ void __launch_bounds__(256) k_conv1(const int* __restrict__ tf,
                                               const float* __restrict__ w1,
                                               unsigned* __restrict__ pbf) {
  __shared__ int tf_s[2 * 5 * 260];          // [ci][kh][col], col = ww+2
  const int h = blockIdx.x;
  const int c0 = blockIdx.y * 4;
  const int tid = threadIdx.x;
  for (int j = tid; j < 2 * 5 * 260; j += 256) {
    int ci = j / 1300, r = (j % 1300) / 260, col = j % 260;
    int hh = h + r - 2, ww = col - 2;
    tf_s[j] = (hh >= 0 && hh < HIN && ww >= 0 && ww < HIN)
                ? tf[ci * HIN * HIN + hh * HIN + ww] : T;
  }
  __syncthreads();
  const int w = tid;
  int t0[50];
  // tap order q = (kh,kw,ci) — the validated accumulation order
#pragma unroll
  for (int kh = 0; kh < 5; kh++)
#pragma unroll
    for (int kw = 0; kw < 5; kw++)
#pragma unroll
      for (int ci = 0; ci < 2; ci++)
        t0[(kh * 5 + kw) * 2 + ci] = tf_s[(ci * 5 + kh) * 260 + w + kw];

  for (int c = c0; c < c0 + 4; c++) {
    float wr[50];
#pragma unroll
    for (int q = 0; q < 50; q++) {
      int ci = q & 1, khkw = q >> 1;
      wr[q] = w1[c * 50 + ci * 25 + khkw];   // khkw = kh*5+kw
    }
    auto ev = [&](int tc) -> float {
      float s = 0.f;
#pragma unroll
      for (int q = 0; q < 50; q++) s += (t0[q] <= tc) ? wr[q] : 0.f;
      return s;
    };
    int t = 0;
    if (!(ev(7)     > 10.0f)) t = 8;
    if (!(ev(t + 3) > 10.0f)) t += 4;
    if (!(ev(t + 1) > 10.0f)) t += 2;
    if (!(ev(t)     > 10.0f)) t += 1;
    pbf[c * CHW * CHW + h * CHW + w] = (unsigned)((0x7FFF << t) & 0x7FFF);
  }
}

// ---------------------------------------------------------------- k2: maxpool(OR) + pointwise inhibition, fused
// packed[h*131+w]: bits0-14 = winner spike train, bits16+ = winner_channel+1 (0 => none)
__global__ void k_inhib1(const unsigned* __restrict__ pbf, unsigned* __restrict__ packed) {
  int i = blockIdx.x * 256 + threadIdx.x;
  if (i >= PADP * PADP) return;
  int wp = i % PADP, hp = i / PADP;
  if (hp == 0 || hp == PADP - 1 || wp == 0 || wp == PADP - 1) { packed[i] = 0; return; }
  int h0 = 2 * (hp - 1) - 1, w0 = 2 * (wp - 1) - 1;
  unsigned seen = 0;
  int fc[T];
#pragma unroll
  for (int t = 0; t < T; t++) fc[t] = 0;
  for (int c = 0; c < C1N; c++) {
    unsigned b = 0;
#pragma unroll
    for (int p = 0; p < 4; p++) {
      int hh = h0 + (p >> 1), ww = w0 + (p & 1);
      if (hh >= 0 && hh < CHW && ww >= 0 && ww < CHW) b |= pbf[c * CHW * CHW + hh * CHW + ww];
    }
    unsigned nb = b & ~seen;
    if (nb) {
#pragma unroll
      for (int t = 0; t < T; t++) if ((nb >> t) & 1u) fc[t] = c;
    }
    seen |= b;
  }
  int cnt = __popc(seen);
  int spiked = (seen >> (T - 1)) & 1u;
  int e = T - cnt; e = e < 0 ? 0 : (e > T - 1 ? T - 1 : e);
  int win = 0;
#pragma unroll
  for (int t = 0; t < T; t++) win = (t == e) ? fc[t] : win;
  unsigned res = 0;
  if (spiked) {
    unsigned wb = 0;
#pragma unroll
    for (int p = 0; p < 4; p++) {
      int hh = h0 + (p >> 1), ww = w0 + (p & 1);
      if (hh >= 0 && hh < CHW && ww >= 0 && ww < CHW) wb |= pbf[win * CHW * CHW + hh * CHW + ww];
    }
    res = wb | ((unsigned)(win + 1) << 16);
  }
  packed[i] = res;
}

// ---------------------------------------------------------------- k3: transpose w2 -> w2t[o][f], o = c*4 + kh*2 + kw
__global__ void k_w2t(const float* __restrict__ w2, float* __restrict__ w2t) {
  int i = blockIdx.x * 256 + threadIdx.x;
  if (i >= C2N * 128) return;
  int f = i / 128, o = i % 128;
  w2t[o * C2N + f] = w2[i];
}

// ---------------------------------------------------------------- k4: wave per (t,pos): conv2 on the fly + fire(1) -> channel max/argmax
__global__ void __launch_bounds__(256) k_score(const unsigned* __restrict__ packed,
                                               const float* __restrict__ w2t,
                                               float* __restrict__ mx, int* __restrict__ mi) {
  int item = blockIdx.x * 4 + (threadIdx.x >> 6);
  int lane = threadIdx.x & 63;
  if (item >= T * POS2) return;
  int pos = item % POS2, t = item / POS2;
  int h = pos / HO, w = pos % HO;
  unsigned pk0 = packed[h * PADP + w],       pk1 = packed[h * PADP + w + 1];
  unsigned pk2 = packed[(h + 1) * PADP + w], pk3 = packed[(h + 1) * PADP + w + 1];
  int c0 = (int)(pk0 >> 16) - 1, c1 = (int)(pk1 >> 16) - 1;
  int c2 = (int)(pk2 >> 16) - 1, c3 = (int)(pk3 >> 16) - 1;
  bool a0 = (c0 >= 0) && ((pk0 >> t) & 1u), a1 = (c1 >= 0) && ((pk1 >> t) & 1u);
  bool a2 = (c2 >= 0) && ((pk2 >> t) & 1u), a3 = (c3 >= 0) && ((pk3 >> t) & 1u);
  const float* r0 = w2t + ((c0 >= 0 ? c0 : 0) * 4 + 0) * C2N;
  const float* r1 = w2t + ((c1 >= 0 ? c1 : 0) * 4 + 1) * C2N;
  const float* r2 = w2t + ((c2 >= 0 ? c2 : 0) * 4 + 2) * C2N;
  const float* r3 = w2t + ((c3 >= 0 ? c3 : 0) * 4 + 3) * C2N;
  float bmx = -1.f; int bmi = 0;
#pragma unroll
  for (int k = 0; k < 3; k++) {
    int f = lane + 64 * k;
    if (f < C2N) {
      float s = 0.f;                     // tap order p=0..3 = (kh,kw) — ref reduction order
      s += a0 ? r0[f] : 0.f;
      s += a1 ? r1[f] : 0.f;
      s += a2 ? r2[f] : 0.f;
      s += a3 ? r3[f] : 0.f;
      float v = (s > 1.0f) ? s : 0.f;
      if (v > bmx) { bmx = v; bmi = f; } // ascending f + strict > => first index on ties
    }
  }
#pragma unroll
  for (int off = 32; off > 0; off >>= 1) {
    float ov = __shfl_xor(bmx, off);
    int   oi = __shfl_xor(bmi, off);
    if (ov > bmx || (ov == bmx && oi < bmi)) { bmx = ov; bmi = oi; }
  }
  if (lane == 0) { mx[item] = bmx; mi[item] = bmi; }
}

// ---------------------------------------------------------------- k5: per pos: winner channel + k-winner stats
__global__ void k_winpos(const float* __restrict__ mx, const int* __restrict__ mi,
                         const unsigned* __restrict__ packed, const float* __restrict__ w2,
                         int* __restrict__ win2, float* __restrict__ val2, int* __restrict__ nspk2) {
  int pos = blockIdx.x * 256 + threadIdx.x;
  if (pos >= POS2) return;
  float m[T]; int q[T];
#pragma unroll
  for (int t = 0; t < T; t++) { m[t] = mx[t * POS2 + pos]; q[t] = mi[t * POS2 + pos]; }
  int cnt = 0;
#pragma unroll
  for (int t = 0; t < T; t++) cnt += (m[t] > 0.f) ? 1 : 0;
  int spiked = (m[T - 1] > 0.f) ? 1 : 0;
  int e = T - cnt; e = e < 0 ? 0 : (e > T - 1 ? T - 1 : e);
  int win = 0;
#pragma unroll
  for (int t = 0; t < T; t++) win = (t == e) ? q[t] : win;
  if (!spiked) win = -1;

  int h = pos / HO, w = pos % HO;
  unsigned pk0 = packed[h * PADP + w],       pk1 = packed[h * PADP + w + 1];
  unsigned pk2 = packed[(h + 1) * PADP + w], pk3 = packed[(h + 1) * PADP + w + 1];
  int c0 = (int)(pk0 >> 16) - 1, c1 = (int)(pk1 >> 16) - 1;
  int c2 = (int)(pk2 >> 16) - 1, c3 = (int)(pk3 >> 16) - 1;
  float wv0 = 0.f, wv1 = 0.f, wv2 = 0.f, wv3 = 0.f;
  if (win >= 0) {
    const float* wf = w2 + win * 128;
    wv0 = (c0 >= 0) ? wf[c0 * 4 + 0] : 0.f;
    wv1 = (c1 >= 0) ? wf[c1 * 4 + 1] : 0.f;
    wv2 = (c2 >= 0) ? wf[c2 * 4 + 2] : 0.f;
    wv3 = (c3 >= 0) ? wf[c3 * 4 + 3] : 0.f;
  }
  float pv[T];
#pragma unroll
  for (int t = 0; t < T; t++) {
    float s = 0.f;
    s += ((pk0 >> t) & 1u) ? wv0 : 0.f;
    s += ((pk1 >> t) & 1u) ? wv1 : 0.f;
    s += ((pk2 >> t) & 1u) ? wv2 : 0.f;
    s += ((pk3 >> t) & 1u) ? wv3 : 0.f;
    pv[t] = (win >= 0 && s > 1.0f) ? s : 0.f;
  }
  int n = 0;
#pragma unroll
  for (int t = 0; t < T; t++) n += (pv[t] > 0.f) ? 1 : 0;
  int e2 = T - n; e2 = e2 < 0 ? 0 : (e2 > T - 1 ? T - 1 : e2);
  float vv = 0.f;
#pragma unroll
  for (int t = 0; t < T; t++) vv = (t == e2) ? pv[t] : vv;
  win2[pos] = win; val2[pos] = vv; nspk2[pos] = n;
}

// ---------------------------------------------------------------- k6: get_k_winners (single block, shfl-butterfly argmax)
__global__ void __launch_bounds__(1024) k_kwin(const int* __restrict__ win2,
                                               const float* __restrict__ val2,
                                               const int* __restrict__ nspk2,
                                               float* __restrict__ wout) {
  const int NE = 17;  // ceil(16900/1024)
  int tid = threadIdx.x;
  int lane = tid & 63, wid = tid >> 6;
  float tot[NE]; int wch[NE]; float vr[NE]; int nr[NE];
  float vmax = 0.f;
#pragma unroll
  for (int j = 0; j < NE; j++) {
    int i = tid + j * 1024;
    bool ok = (i < POS2);
    wch[j] = ok ? win2[i] : -1;
    vr[j]  = ok ? val2[i] : 0.f;
    nr[j]  = ok ? nspk2[i] : 0;
    if (nr[j] > 0 && vr[j] > vmax) vmax = vr[j];
  }
  __shared__ float sred[16];
  __shared__ float sbc[1];
  __shared__ float svv[16]; __shared__ int sii[16];
  __shared__ int sres[2];
  __shared__ float swin[24];
#pragma unroll
  for (int off = 32; off > 0; off >>= 1) vmax = fmaxf(vmax, __shfl_xor(vmax, off));
  if (lane == 0) sred[wid] = vmax;
  __syncthreads();
  if (tid == 0) {
    float mm = sred[0];
    for (int k = 1; k < 16; k++) mm = fmaxf(mm, sred[k]);
    sbc[0] = mm * 15.f;                  // v = trunc.max() * T
  }
  __syncthreads();
  float v = sbc[0];
#pragma unroll
  for (int j = 0; j < NE; j++) tot[j] = (float)nr[j] * (vr[j] + v);

  for (int k = 0; k < 8; k++) {
    float bm = 0.f; int bi = 0x7FFFFFFF;
#pragma unroll
    for (int j = 0; j < NE; j++) {
      int i = tid + j * 1024;
      int fl = wch[j] * POS2 + i;        // reference flat index c*16900 + h*130 + w
      bool better = (tot[j] > bm) || (tot[j] == bm && fl < bi);
      if (better) { bm = tot[j]; bi = fl; }
    }
#pragma unroll
    for (int off = 32; off > 0; off >>= 1) {
      float ov = __shfl_xor(bm, off); int oi = __shfl_xor(bi, off);
      if (ov > bm || (ov == bm && oi < bi)) { bm = ov; bi = oi; }
    }
    if (lane == 0) { svv[wid] = bm; sii[wid] = bi; }
    __syncthreads();
    if (tid == 0) {
      float mb = svv[0]; int mj = sii[0];
      for (int u = 1; u < 16; u++)
        if (svv[u] > mb || (svv[u] == mb && sii[u] < mj)) { mb = svv[u]; mj = sii[u]; }
      sres[0] = __float_as_int(mb); sres[1] = mj;
      int c = mj / POS2, pos = mj % POS2, r = pos / HO, qq = pos % HO;
      if (mb != 0.f) { swin[k*3] = (float)c; swin[k*3+1] = (float)r; swin[k*3+2] = (float)qq; }
      else           { swin[k*3] = -1.f;     swin[k*3+1] = -1.f;     swin[k*3+2] = -1.f;     }
    }
    __syncthreads();
    float mval = __int_as_float(sres[0]); int midx = sres[1];
    if (mval != 0.f) {
      int c = midx / POS2, pos = midx % POS2, r = pos / HO, qq = pos % HO;
#pragma unroll
      for (int j = 0; j < NE; j++) {
        int i = tid + j * 1024;
        int hh = i / HO, ww = i % HO;
        bool kill = (wch[j] == c) || (hh >= r - 1 && hh <= r + 1 && ww >= qq - 1 && ww <= qq + 1);
        if (kill) tot[j] = 0.f;
      }
    }
    __syncthreads();
  }
  if (tid < 24) wout[tid] = swin[tid];
}

// ---------------------------------------------------------------- k7: final writer — pot2 (winner-only recompute) + spk2, 304 MB
__global__ void __launch_bounds__(256) k_final(const unsigned* __restrict__ packed,
                                               const float* __restrict__ w2,
                                               const int* __restrict__ win2,
                                               float4* __restrict__ pot2, float4* __restrict__ spk2) {
  int i4 = blockIdx.x * 256 + threadIdx.x;
  if (i4 >= NPOT2 / 4) return;
  int p4 = i4 % POS4;
  int c  = (i4 / POS4) % C2N;
  int t  = i4 / (POS4 * C2N);
  int pos0 = p4 * 4;
  int4 wn4 = *reinterpret_cast<const int4*>(win2 + pos0);
  const int* wn = reinterpret_cast<const int*>(&wn4);
  float o[4], sp[4];
#pragma unroll
  for (int j = 0; j < 4; j++) {
    float val = 0.f;
    if (wn[j] == c) {
      int pos = pos0 + j;
      int h = pos / HO, w = pos % HO;
      unsigned pk0 = packed[h * PADP + w],       pk1 = packed[h * PADP + w + 1];
      unsigned pk2 = packed[(h + 1) * PADP + w], pk3 = packed[(h + 1) * PADP + w + 1];
      int c0 = (int)(pk0 >> 16) - 1, c1 = (int)(pk1 >> 16) - 1;
      int c2 = (int)(pk2 >> 16) - 1, c3 = (int)(pk3 >> 16) - 1;
      const float* wf = w2 + c * 128;
      float s = 0.f;
      s += ((c0 >= 0) && ((pk0 >> t) & 1u)) ? wf[(c0 >= 0 ? c0 : 0) * 4 + 0] : 0.f;
      s += ((c1 >= 0) && ((pk1 >> t) & 1u)) ? wf[(c1 >= 0 ? c1 : 0) * 4 + 1] : 0.f;
      s += ((c2 >= 0) && ((pk2 >> t) & 1u)) ? wf[(c2 >= 0 ? c2 : 0) * 4 + 2] : 0.f;
      s += ((c3 >= 0) && ((pk3 >> t) & 1u)) ? wf[(c3 >= 0 ? c3 : 0) * 4 + 3] : 0.f;
      val = (s > 1.0f) ? s : 0.f;
    }
    o[j] = val; sp[j] = (val > 0.f) ? 1.f : 0.f;
  }
  pot2[i4] = make_float4(o[0], o[1], o[2], o[3]);
  spk2[i4] = make_float4(sp[0], sp[1], sp[2], sp[3]);
}

extern "C" void kernel_launch(void* const* d_in, const int* in_sizes, int n_in,
                              void* d_out, int out_size, void* d_ws, size_t ws_size,
                              hipStream_t stream) {
  const float* in = (const float*)d_in[0];
  const float* w1 = (const float*)d_in[1];
  const float* w2 = (const float*)d_in[2];
  (void)in_sizes; (void)n_in; (void)out_size; (void)ws_size;

  float* pot2 = (float*)d_out;                    // chunk 0: [15,150,130,130]
  float* spk2 = pot2 + NPOT2;                     // chunk 1: [15,150,130,130]
  float* wout = pot2 + 2 * (size_t)NPOT2;         // chunk 2: [8,3]

  // small scratch that must survive until k_final -> d_ws (136 KB)
  unsigned* packed = (unsigned*)d_ws;             // 17161 u32
  int*      win2   = (int*)d_ws + 17164;          // 16900 i32, 16B-aligned offset

  // bulky early scratch lives in pot2 chunk (fully consumed before k_final overwrites)
  float* scr = pot2;
  int*      tf    = (int*)     (scr);             // 131072
  unsigned* pbf   = (unsigned*)(scr + 131072);    // 2097152
  float*    w2t   = (float*)   (scr + 2228224);   // 19200
  float*    mx    = (float*)   (scr + 2247424);   // 253500
  int*      mi    = (int*)     (scr + 2500924);   // 253500
  float*    val2  = (float*)   (scr + 2754424);   // 16900
  int*      nspk2 = (int*)     (scr + 2771324);   // 16900

  hipLaunchKernelGGL(k_tfirst, dim3((2 * HIN * HIN + 255) / 256), dim3(256), 0, stream, in, tf);
  hipLaunchKernelGGL(k_conv1,  dim3(CHW, 8), dim3(256), 0, stream, tf, w1, pbf);
  hipLaunchKernelGGL(k_inhib1, dim3((PADP * PADP + 255) / 256), dim3(256), 0, stream, pbf, packed);
  hipLaunchKernelGGL(k_w2t,    dim3((C2N * 128 + 255) / 256), dim3(256), 0, stream, w2, w2t);
  hipLaunchKernelGGL(k_score,  dim3((T * POS2 + 3) / 4), dim3(256), 0, stream, packed, w2t, mx, mi);
  hipLaunchKernelGGL(k_winpos, dim3((POS2 + 255) / 256), dim3(256), 0, stream, mx, mi, packed, w2, win2, val2, nspk2);
  hipLaunchKernelGGL(k_kwin,   dim3(1), dim3(1024), 0, stream, win2, val2, nspk2, wout);
  hipLaunchKernelGGL(k_final,  dim3((NPOT2 / 4 + 255) / 256), dim3(256), 0, stream,
                     packed, w2, win2, (float4*)pot2, (float4*)spk2);
}

// Round 6
// 203.784 us; speedup vs baseline: 1.3778x; 1.3778x over previous
//
#include <hip/hip_runtime.h>

#define T 15
#define HIN 256
#define C1N 32
#define C2N 150
#define CHW 256              // conv1 output spatial
#define PP 129               // pooled spatial
#define PADP 131             // padded pooled
#define HO 130               // conv2 output spatial
#define POS2 (HO*HO)         // 16900
#define POS4 (POS2/4)        // 4225
#define NPOT2 (T*C2N*POS2)   // 38,025,000
#define NF4 (NPOT2/4)        // 9,506,250

typedef float __attribute__((ext_vector_type(4))) f32x4;

// ---------------------------------------------------------------- k0: first-spike time per input pixel
__global__ void k_tfirst(const float* __restrict__ in, int* __restrict__ tf) {
  int i = blockIdx.x * 256 + threadIdx.x;
  if (i >= 2 * HIN * HIN) return;
  float s = 0.f;
#pragma unroll
  for (int t = 0; t < T; t++) s += in[t * (2 * HIN * HIN) + i];
  tf[i] = T - (int)(s + 0.5f);   // cumulative binary input: sum = #active steps
}

// ---------------------------------------------------------------- k1: conv1 + fire(10), LDS-staged taps, 4 channels/thread
__global__ void __launch_bounds__(256) k_conv1(const int* __restrict__ tf,
                                               const float* __restrict__ w1,
                                               unsigned* __restrict__ pbf) {
  __shared__ int tf_s[2 * 5 * 260];          // [ci][kh][col], col = ww+2
  const int h = blockIdx.x;
  const int c0 = blockIdx.y * 4;
  const int tid = threadIdx.x;
  for (int j = tid; j < 2 * 5 * 260; j += 256) {
    int ci = j / 1300, r = (j % 1300) / 260, col = j % 260;
    int hh = h + r - 2, ww = col - 2;
    tf_s[j] = (hh >= 0 && hh < HIN && ww >= 0 && ww < HIN)
                ? tf[ci * HIN * HIN + hh * HIN + ww] : T;
  }
  __syncthreads();
  const int w = tid;
  int t0[50];
  // tap order q = (kh,kw,ci) — the validated accumulation order
#pragma unroll
  for (int kh = 0; kh < 5; kh++)
#pragma unroll
    for (int kw = 0; kw < 5; kw++)
#pragma unroll
      for (int ci = 0; ci < 2; ci++)
        t0[(kh * 5 + kw) * 2 + ci] = tf_s[(ci * 5 + kh) * 260 + w + kw];

  for (int c = c0; c < c0 + 4; c++) {
    float wr[50];
#pragma unroll
    for (int q = 0; q < 50; q++) {
      int ci = q & 1, khkw = q >> 1;
      wr[q] = w1[c * 50 + ci * 25 + khkw];   // khkw = kh*5+kw
    }
    auto ev = [&](int tc) -> float {
      float s = 0.f;
#pragma unroll
      for (int q = 0; q < 50; q++) s += (t0[q] <= tc) ? wr[q] : 0.f;
      return s;
    };
    int t = 0;
    if (!(ev(7)     > 10.0f)) t = 8;
    if (!(ev(t + 3) > 10.0f)) t += 4;
    if (!(ev(t + 1) > 10.0f)) t += 2;
    if (!(ev(t)     > 10.0f)) t += 1;
    pbf[c * CHW * CHW + h * CHW + w] = (unsigned)((0x7FFF << t) & 0x7FFF);
  }
}

// ---------------------------------------------------------------- k2: fused {maxpool+inhibition} and {w2 transpose}
// range A (i < 17161): packed[h*131+w]; bits0-14 winner train, bits16+ = ch+1
// range B: w2t[o][f] transpose
__global__ void k_mid(const unsigned* __restrict__ pbf, unsigned* __restrict__ packed,
                      const float* __restrict__ w2, float* __restrict__ w2t) {
  int i = blockIdx.x * 256 + threadIdx.x;
  if (i < PADP * PADP) {
    int wp = i % PADP, hp = i / PADP;
    if (hp == 0 || hp == PADP - 1 || wp == 0 || wp == PADP - 1) { packed[i] = 0; return; }
    int h0 = 2 * (hp - 1) - 1, w0 = 2 * (wp - 1) - 1;
    unsigned seen = 0;
    int fc[T];
#pragma unroll
    for (int t = 0; t < T; t++) fc[t] = 0;
    for (int c = 0; c < C1N; c++) {
      unsigned b = 0;
#pragma unroll
      for (int p = 0; p < 4; p++) {
        int hh = h0 + (p >> 1), ww = w0 + (p & 1);
        if (hh >= 0 && hh < CHW && ww >= 0 && ww < CHW) b |= pbf[c * CHW * CHW + hh * CHW + ww];
      }
      unsigned nb = b & ~seen;
      if (nb) {
#pragma unroll
        for (int t = 0; t < T; t++) if ((nb >> t) & 1u) fc[t] = c;
      }
      seen |= b;
    }
    int cnt = __popc(seen);
    int spiked = (seen >> (T - 1)) & 1u;
    int e = T - cnt; e = e < 0 ? 0 : (e > T - 1 ? T - 1 : e);
    int win = 0;
#pragma unroll
    for (int t = 0; t < T; t++) win = (t == e) ? fc[t] : win;
    unsigned res = 0;
    if (spiked) {
      unsigned wb = 0;
#pragma unroll
      for (int p = 0; p < 4; p++) {
        int hh = h0 + (p >> 1), ww = w0 + (p & 1);
        if (hh >= 0 && hh < CHW && ww >= 0 && ww < CHW) wb |= pbf[win * CHW * CHW + hh * CHW + ww];
      }
      res = wb | ((unsigned)(win + 1) << 16);
    }
    packed[i] = res;
  } else {
    int i2 = i - PADP * PADP;
    if (i2 >= C2N * 128) return;
    int f = i2 / 128, o = i2 % 128;
    w2t[o * C2N + f] = w2[i2];
  }
}

// ---------------------------------------------------------------- k3: wave per pos: conv2 + fire + per-t argmax + winner + k-winner stats
__global__ void __launch_bounds__(256) k_scorewin(const unsigned* __restrict__ packed,
                                                  const float* __restrict__ w2t,
                                                  const float* __restrict__ w2,
                                                  int* __restrict__ win2, float* __restrict__ val2,
                                                  int* __restrict__ nspk2) {
  int pos = blockIdx.x * 4 + (threadIdx.x >> 6);
  int lane = threadIdx.x & 63;
  if (pos >= POS2) return;
  int h = pos / HO, w = pos % HO;
  unsigned pk0 = packed[h * PADP + w],       pk1 = packed[h * PADP + w + 1];
  unsigned pk2 = packed[(h + 1) * PADP + w], pk3 = packed[(h + 1) * PADP + w + 1];
  int c0 = (int)(pk0 >> 16) - 1, c1 = (int)(pk1 >> 16) - 1;
  int c2 = (int)(pk2 >> 16) - 1, c3 = (int)(pk3 >> 16) - 1;
  const float* r0 = w2t + ((c0 >= 0 ? c0 : 0) * 4 + 0) * C2N;
  const float* r1 = w2t + ((c1 >= 0 ? c1 : 0) * 4 + 1) * C2N;
  const float* r2 = w2t + ((c2 >= 0 ? c2 : 0) * 4 + 2) * C2N;
  const float* r3 = w2t + ((c3 >= 0 ? c3 : 0) * 4 + 3) * C2N;
  const int f0 = lane, f1 = lane + 64, f2 = lane + 128;
  // hoisted weights: one load set per pos, reused over all 15 t
  float wA0 = r0[f0], wA1 = r1[f0], wA2 = r2[f0], wA3 = r3[f0];
  float wB0 = r0[f1], wB1 = r1[f1], wB2 = r2[f1], wB3 = r3[f1];
  float wC0 = 0.f, wC1 = 0.f, wC2 = 0.f, wC3 = 0.f;
  if (f2 < C2N) { wC0 = r0[f2]; wC1 = r1[f2]; wC2 = r2[f2]; wC3 = r3[f2]; }

  float m[T]; int q[T];
#pragma unroll
  for (int t = 0; t < T; t++) {
    bool b0 = (pk0 >> t) & 1u, b1 = (pk1 >> t) & 1u;
    bool b2 = (pk2 >> t) & 1u, b3 = (pk3 >> t) & 1u;
    // tap order p=0..3 = (kh,kw) — ref reduction order (packed bit implies c>=0)
    float sA = 0.f; sA += b0 ? wA0 : 0.f; sA += b1 ? wA1 : 0.f; sA += b2 ? wA2 : 0.f; sA += b3 ? wA3 : 0.f;
    float sB = 0.f; sB += b0 ? wB0 : 0.f; sB += b1 ? wB1 : 0.f; sB += b2 ? wB2 : 0.f; sB += b3 ? wB3 : 0.f;
    float sC = 0.f; sC += b0 ? wC0 : 0.f; sC += b1 ? wC1 : 0.f; sC += b2 ? wC2 : 0.f; sC += b3 ? wC3 : 0.f;
    float vA = (sA > 1.0f) ? sA : 0.f;
    float vB = (sB > 1.0f) ? sB : 0.f;
    float vC = (sC > 1.0f) ? sC : 0.f;
    float bmx = -1.f; int bmi = 0;
    if (vA > bmx) { bmx = vA; bmi = f0; }              // always true: vA >= 0 > -1
    if (vB > bmx) { bmx = vB; bmi = f1; }
    if (f2 < C2N && vC > bmx) { bmx = vC; bmi = f2; }
#pragma unroll
    for (int off = 32; off > 0; off >>= 1) {
      float ov = __shfl_xor(bmx, off);
      int   oi = __shfl_xor(bmi, off);
      if (ov > bmx || (ov == bmx && oi < bmi)) { bmx = ov; bmi = oi; }
    }
    m[t] = bmx; q[t] = bmi;                            // broadcast on all lanes
  }
  // pointwise-inhibition winner for this pos
  int cnt = 0;
#pragma unroll
  for (int t = 0; t < T; t++) cnt += (m[t] > 0.f) ? 1 : 0;
  int spiked = (m[T - 1] > 0.f) ? 1 : 0;
  int e = T - cnt; e = e < 0 ? 0 : (e > T - 1 ? T - 1 : e);
  int win = 0;
#pragma unroll
  for (int t = 0; t < T; t++) win = (t == e) ? q[t] : win;
  if (!spiked) win = -1;
  // k-winner stats from winner channel (wave-uniform scalar loads from w2)
  float wv0 = 0.f, wv1 = 0.f, wv2 = 0.f, wv3 = 0.f;
  if (win >= 0) {
    const float* wf = w2 + win * 128;
    wv0 = (c0 >= 0) ? wf[c0 * 4 + 0] : 0.f;
    wv1 = (c1 >= 0) ? wf[c1 * 4 + 1] : 0.f;
    wv2 = (c2 >= 0) ? wf[c2 * 4 + 2] : 0.f;
    wv3 = (c3 >= 0) ? wf[c3 * 4 + 3] : 0.f;
  }
  float pv[T];
#pragma unroll
  for (int t = 0; t < T; t++) {
    float s = 0.f;
    s += ((pk0 >> t) & 1u) ? wv0 : 0.f;
    s += ((pk1 >> t) & 1u) ? wv1 : 0.f;
    s += ((pk2 >> t) & 1u) ? wv2 : 0.f;
    s += ((pk3 >> t) & 1u) ? wv3 : 0.f;
    pv[t] = (win >= 0 && s > 1.0f) ? s : 0.f;
  }
  int n = 0;
#pragma unroll
  for (int t = 0; t < T; t++) n += (pv[t] > 0.f) ? 1 : 0;
  int e2 = T - n; e2 = e2 < 0 ? 0 : (e2 > T - 1 ? T - 1 : e2);
  float vv = 0.f;
#pragma unroll
  for (int t = 0; t < T; t++) vv = (t == e2) ? pv[t] : vv;
  if (lane == 0) { win2[pos] = win; val2[pos] = vv; nspk2[pos] = n; }
}

// ---------------------------------------------------------------- k4: block 0 = get_k_winners; blocks 1.. = 304 MB final writer
__global__ void __launch_bounds__(1024) k_finalk(const unsigned* __restrict__ packed,
                                                 const float* __restrict__ w2,
                                                 const int* __restrict__ win2,
                                                 const float* __restrict__ val2,
                                                 const int* __restrict__ nspk2,
                                                 f32x4* __restrict__ pot2, f32x4* __restrict__ spk2,
                                                 float* __restrict__ wout) {
  __shared__ float sred[16];
  __shared__ float sbc[1];
  __shared__ float svv[16]; __shared__ int sii[16];
  __shared__ int sres[2];
  __shared__ float swin[24];
  if (blockIdx.x == 0) {
    // ---- get_k_winners (1024 threads, independent of the writer blocks)
    const int NE = 17;
    int tid = threadIdx.x;
    int lane = tid & 63, wid = tid >> 6;
    float tot[NE]; int wch[NE]; float vr[NE]; int nr[NE];
    float vmax = 0.f;
#pragma unroll
    for (int j = 0; j < NE; j++) {
      int i = tid + j * 1024;
      bool ok = (i < POS2);
      wch[j] = ok ? win2[i] : -1;
      vr[j]  = ok ? val2[i] : 0.f;
      nr[j]  = ok ? nspk2[i] : 0;
      if (nr[j] > 0 && vr[j] > vmax) vmax = vr[j];
    }
#pragma unroll
    for (int off = 32; off > 0; off >>= 1) vmax = fmaxf(vmax, __shfl_xor(vmax, off));
    if (lane == 0) sred[wid] = vmax;
    __syncthreads();
    if (tid == 0) {
      float mm = sred[0];
      for (int k = 1; k < 16; k++) mm = fmaxf(mm, sred[k]);
      sbc[0] = mm * 15.f;                // v = trunc.max() * T
    }
    __syncthreads();
    float v = sbc[0];
#pragma unroll
    for (int j = 0; j < NE; j++) tot[j] = (float)nr[j] * (vr[j] + v);

    for (int k = 0; k < 8; k++) {
      float bm = 0.f; int bi = 0x7FFFFFFF;
#pragma unroll
      for (int j = 0; j < NE; j++) {
        int i = tid + j * 1024;
        int fl = wch[j] * POS2 + i;      // reference flat index c*16900 + h*130 + w
        bool better = (tot[j] > bm) || (tot[j] == bm && fl < bi);
        if (better) { bm = tot[j]; bi = fl; }
      }
#pragma unroll
      for (int off = 32; off > 0; off >>= 1) {
        float ov = __shfl_xor(bm, off); int oi = __shfl_xor(bi, off);
        if (ov > bm || (ov == bm && oi < bi)) { bm = ov; bi = oi; }
      }
      if (lane == 0) { svv[wid] = bm; sii[wid] = bi; }
      __syncthreads();
      if (tid == 0) {
        float mb = svv[0]; int mj = sii[0];
        for (int u = 1; u < 16; u++)
          if (svv[u] > mb || (svv[u] == mb && sii[u] < mj)) { mb = svv[u]; mj = sii[u]; }
        sres[0] = __float_as_int(mb); sres[1] = mj;
        int c = mj / POS2, pos = mj % POS2, r = pos / HO, qq = pos % HO;
        if (mb != 0.f) { swin[k*3] = (float)c; swin[k*3+1] = (float)r; swin[k*3+2] = (float)qq; }
        else           { swin[k*3] = -1.f;     swin[k*3+1] = -1.f;     swin[k*3+2] = -1.f;     }
      }
      __syncthreads();
      float mval = __int_as_float(sres[0]); int midx = sres[1];
      if (mval != 0.f) {
        int c = midx / POS2, pos = midx % POS2, r = pos / HO, qq = pos % HO;
#pragma unroll
        for (int j = 0; j < NE; j++) {
          int i = tid + j * 1024;
          int hh = i / HO, ww = i % HO;
          bool kill = (wch[j] == c) || (hh >= r - 1 && hh <= r + 1 && ww >= qq - 1 && ww <= qq + 1);
          if (kill) tot[j] = 0.f;
        }
      }
      __syncthreads();
    }
    if (threadIdx.x < 24) wout[threadIdx.x] = swin[threadIdx.x];
  } else {
    // ---- final writer: pot2 (winner-only recompute) + spk2
    int i4 = (blockIdx.x - 1) * 1024 + threadIdx.x;
    if (i4 >= NF4) return;
    int p4 = i4 % POS4;
    int c  = (i4 / POS4) % C2N;
    int t  = i4 / (POS4 * C2N);
    int pos0 = p4 * 4;
    int4 wn4 = *reinterpret_cast<const int4*>(win2 + pos0);
    const int* wn = reinterpret_cast<const int*>(&wn4);
    float o[4], sp[4];
#pragma unroll
    for (int j = 0; j < 4; j++) {
      float val = 0.f;
      if (wn[j] == c) {
        int pos = pos0 + j;
        int h = pos / HO, w = pos % HO;
        unsigned pk0 = packed[h * PADP + w],       pk1 = packed[h * PADP + w + 1];
        unsigned pk2 = packed[(h + 1) * PADP + w], pk3 = packed[(h + 1) * PADP + w + 1];
        int c0 = (int)(pk0 >> 16) - 1, c1 = (int)(pk1 >> 16) - 1;
        int c2 = (int)(pk2 >> 16) - 1, c3 = (int)(pk3 >> 16) - 1;
        const float* wf = w2 + c * 128;
        float s = 0.f;
        s += ((c0 >= 0) && ((pk0 >> t) & 1u)) ? wf[(c0 >= 0 ? c0 : 0) * 4 + 0] : 0.f;
        s += ((c1 >= 0) && ((pk1 >> t) & 1u)) ? wf[(c1 >= 0 ? c1 : 0) * 4 + 1] : 0.f;
        s += ((c2 >= 0) && ((pk2 >> t) & 1u)) ? wf[(c2 >= 0 ? c2 : 0) * 4 + 2] : 0.f;
        s += ((c3 >= 0) && ((pk3 >> t) & 1u)) ? wf[(c3 >= 0 ? c3 : 0) * 4 + 3] : 0.f;
        val = (s > 1.0f) ? s : 0.f;
      }
      o[j] = val; sp[j] = (val > 0.f) ? 1.f : 0.f;
    }
    f32x4 ov = { o[0], o[1], o[2], o[3] };
    f32x4 sv = { sp[0], sp[1], sp[2], sp[3] };
    __builtin_nontemporal_store(ov, pot2 + i4);
    __builtin_nontemporal_store(sv, spk2 + i4);
  }
}

extern "C" void kernel_launch(void* const* d_in, const int* in_sizes, int n_in,
                              void* d_out, int out_size, void* d_ws, size_t ws_size,
                              hipStream_t stream) {
  const float* in = (const float*)d_in[0];
  const float* w1 = (const float*)d_in[1];
  const float* w2 = (const float*)d_in[2];
  (void)in_sizes; (void)n_in; (void)out_size; (void)ws_size;

  float* pot2 = (float*)d_out;                    // chunk 0: [15,150,130,130]
  float* spk2 = pot2 + NPOT2;                     // chunk 1: [15,150,130,130]
  float* wout = pot2 + 2 * (size_t)NPOT2;         // chunk 2: [8,3]

  // scratch that must survive into k_finalk -> d_ws (~275 KB; ws is ~900 MB per poison size)
  unsigned* packed = (unsigned*)d_ws;             // 17161 u32
  int*      win2   = (int*)d_ws + 17164;          // 16900 (offset 16B-aligned)
  float*    val2   = (float*)d_ws + 34064;        // 16900
  int*      nspk2  = (int*)d_ws + 50964;          // 16900

  // bulky early scratch in pot2 chunk (fully consumed before k_finalk's writers run...
  // NOTE: k_finalk block 0 reads only d_ws, so the concurrent overwrite of pot2 is safe)
  float* scr = pot2;
  int*      tf    = (int*)     (scr);             // 131072
  unsigned* pbf   = (unsigned*)(scr + 131072);    // 2097152
  float*    w2t   = (float*)   (scr + 2228224);   // 19200

  hipLaunchKernelGGL(k_tfirst, dim3((2 * HIN * HIN + 255) / 256), dim3(256), 0, stream, in, tf);
  hipLaunchKernelGGL(k_conv1,  dim3(CHW, 8), dim3(256), 0, stream, tf, w1, pbf);
  hipLaunchKernelGGL(k_mid,    dim3((PADP * PADP + C2N * 128 + 255) / 256), dim3(256), 0, stream,
                     pbf, packed, w2, w2t);
  hipLaunchKernelGGL(k_scorewin, dim3(POS2 / 4), dim3(256), 0, stream,
                     packed, w2t, w2, win2, val2, nspk2);
  hipLaunchKernelGGL(k_finalk, dim3(1 + (NF4 + 1023) / 1024), dim3(1024), 0, stream,
                     packed, w2, win2, val2, nspk2, (f32x4*)pot2, (f32x4*)spk2, wout);
}